// Round 11
// baseline (693.824 us; speedup 1.0000x reference)
//
#include <hip/hip_runtime.h>
#include <hip/hip_cooperative_groups.h>

namespace cg = cooperative_groups;

// ---------------------------------------------------------------------------
// GAT GNN: h0 = relu(GAT0(x)); h1 = relu(GAT1(h0));
// out = [x@We+be  ||  h1@Wn+bn]
// R11: single cooperative persistent kernel — 8 phases over grid.sync()
//      replaces 6-9 dispatches (~4-5us/boundary measured across R5-R9).
//      CSR reverted to two-phase (R10's atomic->dependent-scattered-store
//      bucket write doubled the atomic phase; R8: pure atomics are
//      occupancy-insensitive, chains are not). Phase P1 co-schedules
//      [scat1 || gemm0+att0 || proj_ego]; fp32->bf16 A-cast in-register.
// Evidence: agg is gather-service-bound (R6,R9 neutral); scat1 is
// fabric-atomic-bound (R7 vs R8); boundaries ~4-5us each (R5..R9 slope).
// ---------------------------------------------------------------------------

#define LEAKY_SLOPE 0.2f

typedef __attribute__((ext_vector_type(8))) short s16x8;
typedef __attribute__((ext_vector_type(4))) float f32x4;

static __device__ __forceinline__ unsigned short f2bf(float f)
{
    unsigned x = __float_as_uint(f);
    unsigned r = (x + 0x7fffu + ((x >> 16) & 1u)) >> 16;   // RNE
    return (unsigned short)r;
}
static __device__ __forceinline__ float bfhi(unsigned u) { return __uint_as_float(u & 0xffff0000u); }
static __device__ __forceinline__ float bflo(unsigned u) { return __uint_as_float(u << 16); }
static __device__ __forceinline__ uint4 cvt8(float4 v0, float4 v1)
{
    uint4 o;
    o.x = (unsigned)f2bf(v0.x) | ((unsigned)f2bf(v0.y) << 16);
    o.y = (unsigned)f2bf(v0.z) | ((unsigned)f2bf(v0.w) << 16);
    o.z = (unsigned)f2bf(v1.x) | ((unsigned)f2bf(v1.y) << 16);
    o.w = (unsigned)f2bf(v1.z) | ((unsigned)f2bf(v1.w) << 16);
    return o;
}

// ---------------- MFMA GEMM body (BN=128) + fused attention logits ---------
// AF32: A read fp32, cast in-register. HATT=4: layer0 logits. HATT=1: layer1.
// LDS: As 18432 + Bs 33280 + smS/smD 1024 = 52736 B.
template<int HATT, bool AF32>
static __device__ __forceinline__ void gemm128_body(int tile, char* ldsraw,
                                                    const float* __restrict__ Af,
                                                    const unsigned short* __restrict__ Ab,
                                                    const unsigned short* __restrict__ Bp,
                                                    unsigned short* __restrict__ Cb,
                                                    const float* __restrict__ ats,
                                                    const float* __restrict__ atd,
                                                    float* __restrict__ a_s,
                                                    float* __restrict__ a_d, int n)
{
    constexpr int BN = 128;
    constexpr int APITCH = 144;
    constexpr int BPITCH = BN + 2;

    unsigned short* As = (unsigned short*)ldsraw;
    unsigned short* Bs = As + 64 * APITCH;
    float* smS = (float*)(Bs + 16 * BPITCH * 8);
    float* smD = smS + 128;

    const int t  = threadIdx.x;
    const int rb = tile * 64;

#pragma unroll
    for (int i = 0; i < 4; ++i) {
        int q = t + i * 256;
        int r = q >> 4;
        int c = (q & 15) * 8;
        int gr = rb + r;
        if (AF32) {
            float4 v0 = make_float4(0.f, 0.f, 0.f, 0.f);
            float4 v1 = v0;
            if (gr < n) {
                v0 = *(const float4*)(Af + (size_t)gr * 128 + c);
                v1 = *(const float4*)(Af + (size_t)gr * 128 + c + 4);
            }
            *(uint4*)(As + r * APITCH + c) = cvt8(v0, v1);
        } else {
            float4 v = make_float4(0.f, 0.f, 0.f, 0.f);
            if (gr < n) v = *(const float4*)(Ab + (size_t)gr * 128 + c);
            *(float4*)(As + r * APITCH + c) = v;
        }
    }
#pragma unroll
    for (int i = 0; i < 8; ++i) {
        int ge = t + i * 256;
        int o = ge / BN, nn = ge % BN;
        *(float4*)(Bs + ((size_t)o * BPITCH + nn) * 8) = *(const float4*)(Bp + (size_t)ge * 8);
    }
    __syncthreads();

    const int w = t >> 6, lane = t & 63;
    const int m = lane & 15, quad = lane >> 4;
    const int wc = w & 1, wr = w >> 1;
    const int row0 = wr * 32;
    const int col0 = wc * 64;

    f32x4 acc[2][4];
#pragma unroll
    for (int rt = 0; rt < 2; ++rt)
#pragma unroll
        for (int c = 0; c < 4; ++c) acc[rt][c] = (f32x4){0.f, 0.f, 0.f, 0.f};

    s16x8 a[2][4];
#pragma unroll
    for (int rt = 0; rt < 2; ++rt)
#pragma unroll
        for (int kk = 0; kk < 4; ++kk)
            a[rt][kk] = *(const s16x8*)(As + (row0 + rt * 16 + m) * APITCH + kk * 32 + quad * 8);

#pragma unroll
    for (int kk = 0; kk < 4; ++kk)
#pragma unroll
        for (int c = 0; c < 4; ++c) {
            s16x8 b = *(const s16x8*)(Bs + ((size_t)(kk * 4 + quad) * BPITCH + col0 + c * 16 + m) * 8);
#pragma unroll
            for (int rt = 0; rt < 2; ++rt)
                acc[rt][c] = __builtin_amdgcn_mfma_f32_16x16x32_bf16(a[rt][kk], b, acc[rt][c], 0, 0, 0);
        }

    // C store (C/D layout: col=lane&15, row=quad*4+reg)
#pragma unroll
    for (int rt = 0; rt < 2; ++rt)
#pragma unroll
        for (int c = 0; c < 4; ++c)
#pragma unroll
            for (int r = 0; r < 4; ++r) {
                int row = rb + row0 + rt * 16 + quad * 4 + r;
                int colg = col0 + c * 16 + m;
                if (row < n) Cb[(size_t)row * 128 + colg] = f2bf(acc[rt][c][r]);
            }

    // fused attention logits
    float atsv[4], atdv[4];
#pragma unroll
    for (int c = 0; c < 4; ++c) {
        atsv[c] = ats[col0 + c * 16 + m];
        atdv[c] = atd[col0 + c * 16 + m];
    }
    if (HATT == 4) {
#pragma unroll
        for (int rt = 0; rt < 2; ++rt)
#pragma unroll
            for (int r = 0; r < 4; ++r)
#pragma unroll
                for (int hb = 0; hb < 2; ++hb) {
                    float ps = acc[rt][2*hb][r] * atsv[2*hb] + acc[rt][2*hb+1][r] * atsv[2*hb+1];
                    float pd = acc[rt][2*hb][r] * atdv[2*hb] + acc[rt][2*hb+1][r] * atdv[2*hb+1];
#pragma unroll
                    for (int off = 1; off < 16; off <<= 1) {
                        ps += __shfl_xor(ps, off);
                        pd += __shfl_xor(pd, off);
                    }
                    int row = rb + row0 + rt * 16 + quad * 4 + r;
                    if (m == 0 && row < n) {
                        a_s[(size_t)row * 4 + 2*wc + hb] = ps;
                        a_d[(size_t)row * 4 + 2*wc + hb] = pd;
                    }
                }
    }
    if (HATT == 1) {
#pragma unroll
        for (int rt = 0; rt < 2; ++rt)
#pragma unroll
            for (int r = 0; r < 4; ++r) {
                float ps = 0.f, pd = 0.f;
#pragma unroll
                for (int c = 0; c < 4; ++c) {
                    ps = fmaf(acc[rt][c][r], atsv[c], ps);
                    pd = fmaf(acc[rt][c][r], atdv[c], pd);
                }
#pragma unroll
                for (int off = 1; off < 16; off <<= 1) {
                    ps += __shfl_xor(ps, off);
                    pd += __shfl_xor(pd, off);
                }
                int lrow = row0 + rt * 16 + quad * 4 + r;
                if (m == 0) { smS[lrow * 2 + wc] = ps; smD[lrow * 2 + wc] = pd; }
            }
        __syncthreads();
        if (t < 64) {
            int row = rb + t;
            if (row < n) {
                a_s[row] = smS[t * 2] + smS[t * 2 + 1];
                a_d[row] = smD[t * 2] + smD[t * 2 + 1];
            }
        }
    }
}

// ---------------- projection GEMM body (BN=64) -----------------------------
template<bool AF32>
static __device__ __forceinline__ void proj64_body(int tile, char* ldsraw,
                                                   const float* __restrict__ Af,
                                                   const unsigned short* __restrict__ Ab,
                                                   const unsigned short* __restrict__ Bp,
                                                   const float* __restrict__ bias,
                                                   float* __restrict__ Cf, int n)
{
    constexpr int BN = 64;
    constexpr int APITCH = 144;
    constexpr int BPITCH = BN + 2;

    unsigned short* As = (unsigned short*)ldsraw;
    unsigned short* Bs = As + 64 * APITCH;

    const int t  = threadIdx.x;
    const int rb = tile * 64;

#pragma unroll
    for (int i = 0; i < 4; ++i) {
        int q = t + i * 256;
        int r = q >> 4;
        int c = (q & 15) * 8;
        int gr = rb + r;
        if (AF32) {
            float4 v0 = make_float4(0.f, 0.f, 0.f, 0.f);
            float4 v1 = v0;
            if (gr < n) {
                v0 = *(const float4*)(Af + (size_t)gr * 128 + c);
                v1 = *(const float4*)(Af + (size_t)gr * 128 + c + 4);
            }
            *(uint4*)(As + r * APITCH + c) = cvt8(v0, v1);
        } else {
            float4 v = make_float4(0.f, 0.f, 0.f, 0.f);
            if (gr < n) v = *(const float4*)(Ab + (size_t)gr * 128 + c);
            *(float4*)(As + r * APITCH + c) = v;
        }
    }
#pragma unroll
    for (int i = 0; i < 4; ++i) {
        int ge = t + i * 256;
        int o = ge / BN, nn = ge % BN;
        *(float4*)(Bs + ((size_t)o * BPITCH + nn) * 8) = *(const float4*)(Bp + (size_t)ge * 8);
    }
    __syncthreads();

    const int w = t >> 6, lane = t & 63;
    const int m = lane & 15, quad = lane >> 4;
    const int row0 = w * 16;

    f32x4 acc[4];
#pragma unroll
    for (int c = 0; c < 4; ++c) acc[c] = (f32x4){0.f, 0.f, 0.f, 0.f};

    s16x8 a[4];
#pragma unroll
    for (int kk = 0; kk < 4; ++kk)
        a[kk] = *(const s16x8*)(As + (row0 + m) * APITCH + kk * 32 + quad * 8);

#pragma unroll
    for (int kk = 0; kk < 4; ++kk)
#pragma unroll
        for (int c = 0; c < 4; ++c) {
            s16x8 b = *(const s16x8*)(Bs + ((size_t)(kk * 4 + quad) * BPITCH + c * 16 + m) * 8);
            acc[c] = __builtin_amdgcn_mfma_f32_16x16x32_bf16(a[kk], b, acc[c], 0, 0, 0);
        }

#pragma unroll
    for (int c = 0; c < 4; ++c)
#pragma unroll
        for (int r = 0; r < 4; ++r) {
            int row = rb + row0 + quad * 4 + r;
            int colg = c * 16 + m;
            if (row < n) Cf[(size_t)row * BN + colg] = acc[c][r] + bias[colg];
        }
}

// ---------------- GAT aggregation body (16 lanes/edge, dwordx4) ------------
template<int H>
static __device__ __forceinline__ void agg_body(int node, int p0, int deg,
                                                const unsigned short* __restrict__ xlb,
                                                const float* __restrict__ a_s,
                                                const float* __restrict__ a_d,
                                                const int* __restrict__ colv,
                                                const float* __restrict__ bias,
                                                unsigned short* __restrict__ outb)
{
    int lane = threadIdx.x & 63;
    const int sub = lane >> 4, sl = lane & 15;
    const int h = (H == 1) ? 0 : (sl >> 2);          // 8 ch/lane, C=32 per head
    float ad = a_d[(size_t)node * H + h];
    const int* cf = colv + p0;
    float acc[8];
#pragma unroll
    for (int i = 0; i < 8; ++i) acc[i] = 0.f;
    float den = 0.f;
    const unsigned short* xlj = xlb + 8 * sl;

    for (int base = 0; base < deg; base += 64) {
        int m = deg - base;
        if (m > 64) m = 64;
        int cv = cf[base + (lane < m ? lane : m - 1)];
        int nb = (m + 31) >> 5;
        for (int kk = 0; kk < nb; ++kk) {
            int s[8]; float as[8]; uint4 uv[8]; bool val[8];
#pragma unroll
            for (int q = 0; q < 8; ++q) {
                int e = ((kk * 8 + q) << 2) + sub;   // interleaved mod-4
                val[q] = e < m;
                s[q] = __shfl(cv, val[q] ? e : 0);
            }
#pragma unroll
            for (int q = 0; q < 8; ++q) as[q] = a_s[(size_t)s[q] * H + h];
#pragma unroll
            for (int q = 0; q < 8; ++q) uv[q] = *(const uint4*)(xlj + (size_t)s[q] * 128);
#pragma unroll
            for (int q = 0; q < 8; ++q) {
                float al = as[q] + ad;
                al = (al >= 0.f) ? al : LEAKY_SLOPE * al;
                float w = val[q] ? __expf(al) : 0.f;
                den += w;
                acc[0] = fmaf(w, bflo(uv[q].x), acc[0]);
                acc[1] = fmaf(w, bfhi(uv[q].x), acc[1]);
                acc[2] = fmaf(w, bflo(uv[q].y), acc[2]);
                acc[3] = fmaf(w, bfhi(uv[q].y), acc[3]);
                acc[4] = fmaf(w, bflo(uv[q].z), acc[4]);
                acc[5] = fmaf(w, bfhi(uv[q].z), acc[5]);
                acc[6] = fmaf(w, bflo(uv[q].w), acc[6]);
                acc[7] = fmaf(w, bfhi(uv[q].w), acc[7]);
            }
        }
    }

#pragma unroll
    for (int i = 0; i < 8; ++i) {
        acc[i] += __shfl_xor(acc[i], 16);
        acc[i] += __shfl_xor(acc[i], 32);
    }
    den += __shfl_xor(den, 16);
    den += __shfl_xor(den, 32);

    if (sub == 0) {
        float inv = 1.0f / (den + 1e-16f);
        int j = 8 * sl;
        unsigned pk[4];
#pragma unroll
        for (int i = 0; i < 4; ++i) {
            float o0 = fmaxf(fmaf(acc[2*i],     inv, bias[j + 2*i]),     0.f);
            float o1 = fmaxf(fmaf(acc[2*i + 1], inv, bias[j + 2*i + 1]), 0.f);
            pk[i] = (unsigned)f2bf(o0) | ((unsigned)f2bf(o1) << 16);
        }
        *(uint4*)(outb + (size_t)node * 128 + j) = make_uint4(pk[0], pk[1], pk[2], pk[3]);
    }
}

// ---------------- parameter block ------------------------------------------
struct GP {
    const float* x; const int* ei;
    const float* W0; const float* as0; const float* ad0; const float* b0;
    const float* W1; const float* as1; const float* ad1; const float* b1;
    const float* Wn; const float* bn; const float* We; const float* be;
    float* out;
    unsigned short *xlb, *hb, *P0, *P1, *Pn, *Pe;
    float *a_s, *a_d;
    int *curs, *rowe, *slot, *colv, *bsum, *boff;
    int n, E;
};

// ---------------- the whole pipeline, one cooperative kernel ---------------
__global__ __launch_bounds__(256, 3) void coop_k(GP p)
{
    __shared__ __align__(16) char lds[52736];
    cg::grid_group g = cg::this_grid();
    const int tid = threadIdx.x, bid = blockIdx.x, grd = gridDim.x;
    const int n = p.n, E = p.E, ET = E + n;
    const int gE   = (ET + 255) >> 8;
    const int gN64 = (n + 63) >> 6;
    const int NV   = (n + 3) >> 2;
    const int NB   = (n + 255) >> 8;     // <= 256 assumed (n <= 65536)
    int* sm = (int*)lds;

    // ---- P0: pack weights + zero cursors ----
    {
        int W = 49152 + n * 16;
        for (int i = bid * 256 + tid; i < W; i += grd * 256) {
            if (i < 49152) {
                const float* S; unsigned short* D; int BN; int local;
                if (i < 16384)      { S = p.W0; D = p.P0; BN = 128; local = i; }
                else if (i < 32768) { S = p.W1; D = p.P1; BN = 128; local = i - 16384; }
                else if (i < 40960) { S = p.Wn; D = p.Pn; BN = 64;  local = i - 32768; }
                else                { S = p.We; D = p.Pe; BN = 64;  local = i - 40960; }
                int k = local / BN, c = local % BN;
                D[(((k >> 3) * BN + c) * 8) + (k & 7)] = f2bf(S[local]);
            } else {
                p.curs[i - 49152] = 0;
            }
        }
    }
    g.sync();

    // ---- P1: [scat1 || gemm0+att0 || proj_ego] ----
    {
        int vbTot = gE + 2 * gN64;
        for (int vb = bid; vb < vbTot; vb += grd) {
            __syncthreads();                         // protect LDS across iters
            if (vb < gE) {
                int e = vb * 256 + tid;
                if (e < ET) {
                    int d = (e < E) ? p.ei[E + e] : (e - E);  // self-loop dst=node
                    p.slot[e] = atomicAdd(&p.curs[d << 4], 1);
                }
            } else if (vb < gE + gN64) {
                gemm128_body<4, true>(vb - gE, lds, p.x, nullptr, p.P0, p.xlb,
                                      p.as0, p.ad0, p.a_s, p.a_d, n);
            } else {
                proj64_body<true>(vb - gE - gN64, lds, p.x, nullptr, p.Pe, p.be, p.out, n);
            }
        }
    }
    g.sync();

    // ---- P2a: per-chunk exclusive scan of degrees ----
    for (int vb = bid; vb < NB; vb += grd) {
        __syncthreads();
        int i = vb * 256 + tid;
        int v = (i < n) ? p.curs[i << 4] : 0;
        sm[tid] = v;
        __syncthreads();
        for (int off = 1; off < 256; off <<= 1) {
            int xv = (tid >= off) ? sm[tid - off] : 0;
            __syncthreads();
            sm[tid] += xv;
            __syncthreads();
        }
        if (i < n) p.rowe[i] = sm[tid] - v;
        if (tid == 255) p.bsum[vb] = sm[tid];
    }
    g.sync();

    // ---- P2b: block 0 scans the chunk sums ----
    if (bid == 0) {
        int v = (tid < NB) ? p.bsum[tid] : 0;
        sm[tid] = v;
        __syncthreads();
        for (int off = 1; off < 256; off <<= 1) {
            int xv = (tid >= off) ? sm[tid - off] : 0;
            __syncthreads();
            sm[tid] += xv;
            __syncthreads();
        }
        if (tid < NB) p.boff[tid] = sm[tid] - v;
    }
    g.sync();

    // ---- P3: scat2 (atomic-free) ----
    for (int e = bid * 256 + tid; e < ET; e += grd * 256) {
        int s = (e < E) ? p.ei[e]     : (e - E);
        int d = (e < E) ? p.ei[E + e] : (e - E);
        p.colv[p.rowe[d] + p.boff[d >> 8] + p.slot[e]] = s;
    }
    g.sync();

    // ---- P4: layer-0 aggregation ----
    for (int vb = bid; vb < NV; vb += grd) {
        int node = vb * 4 + (tid >> 6);
        if (node < n) {
            int p0v = p.rowe[node] + p.boff[node >> 8];
            int deg = p.curs[node << 4];
            agg_body<4>(node, p0v, deg, p.xlb, p.a_s, p.a_d, p.colv, p.b0, p.hb);
        }
    }
    g.sync();

    // ---- P5: gemm1 + att1 ----
    for (int vb = bid; vb < gN64; vb += grd) {
        __syncthreads();
        gemm128_body<1, false>(vb, lds, nullptr, p.hb, p.P1, p.xlb,
                               p.as1, p.ad1, p.a_s, p.a_d, n);
    }
    g.sync();

    // ---- P6: layer-1 aggregation ----
    for (int vb = bid; vb < NV; vb += grd) {
        int node = vb * 4 + (tid >> 6);
        if (node < n) {
            int p0v = p.rowe[node] + p.boff[node >> 8];
            int deg = p.curs[node << 4];
            agg_body<1>(node, p0v, deg, p.xlb, p.a_s, p.a_d, p.colv, p.b1, p.hb);
        }
    }
    g.sync();

    // ---- P7: h_neighbor projection ----
    for (int vb = bid; vb < gN64; vb += grd) {
        __syncthreads();
        proj64_body<false>(vb, lds, nullptr, p.hb, p.Pn, p.bn,
                           p.out + (size_t)n * 64, n);
    }
}

// ---------------------------------------------------------------------------
extern "C" void kernel_launch(void* const* d_in, const int* in_sizes, int n_in,
                              void* d_out, int out_size, void* d_ws, size_t ws_size,
                              hipStream_t stream)
{
    const int n  = in_sizes[0] / 128;
    const int E  = in_sizes[1] / 2;
    const int ET = E + n;

    char* w = (char*)d_ws;
    auto carve = [&](size_t bytes) -> void* {
        void* p = (void*)w;
        w += (bytes + 255) & ~(size_t)255;
        return p;
    };
    unsigned short* xlb = (unsigned short*)carve((size_t)n * 128 * 2);
    unsigned short* hb  = (unsigned short*)carve((size_t)n * 128 * 2);
    float* a_s  = (float*)carve((size_t)n * 4 * 4);
    float* a_d  = (float*)carve((size_t)n * 4 * 4);
    int*   curs = (int*)carve((size_t)n * 16 * 4);   // padded: 1 counter / 64B
    int*   rowe = (int*)carve((size_t)n * 4);
    int*   slot = (int*)carve((size_t)ET * 4);
    int*   colv = (int*)carve((size_t)ET * 4);
    int*   bsum = (int*)carve(1024);
    int*   boff = (int*)carve(1024);
    unsigned short* P0 = (unsigned short*)carve(16384 * 2);
    unsigned short* P1 = (unsigned short*)carve(16384 * 2);
    unsigned short* Pn = (unsigned short*)carve(8192 * 2);
    unsigned short* Pe = (unsigned short*)carve(8192 * 2);

    GP prm;
    prm.x   = (const float*)d_in[0];
    prm.ei  = (const int*)d_in[1];
    prm.W0  = (const float*)d_in[2];
    prm.as0 = (const float*)d_in[3];
    prm.ad0 = (const float*)d_in[4];
    prm.b0  = (const float*)d_in[5];
    prm.W1  = (const float*)d_in[6];
    prm.as1 = (const float*)d_in[7];
    prm.ad1 = (const float*)d_in[8];
    prm.b1  = (const float*)d_in[9];
    prm.Wn  = (const float*)d_in[10];
    prm.bn  = (const float*)d_in[11];
    prm.We  = (const float*)d_in[12];
    prm.be  = (const float*)d_in[13];
    prm.out = (float*)d_out;
    prm.xlb = xlb; prm.hb = hb;
    prm.P0 = P0; prm.P1 = P1; prm.Pn = Pn; prm.Pe = Pe;
    prm.a_s = a_s; prm.a_d = a_d;
    prm.curs = curs; prm.rowe = rowe; prm.slot = slot; prm.colv = colv;
    prm.bsum = bsum; prm.boff = boff;
    prm.n = n; prm.E = E;

    // grid sized to validated co-residency: 3 blocks/CU (52.7KB LDS) x 256 CUs
    int maxb = 0;
    hipOccupancyMaxActiveBlocksPerMultiprocessor(&maxb, coop_k, 256, 0);
    if (maxb < 1) maxb = 1;
    if (maxb > 3) maxb = 3;
    dim3 grid(maxb * 256);

    void* args[] = { &prm };
    hipLaunchCooperativeKernel((void*)coop_k, grid, dim3(256), args, 0, stream);
}